// Round 1
// baseline (420.167 us; speedup 1.0000x reference)
//
#include <hip/hip_runtime.h>

#define D   128
#define NF  3
#define V   8

// Stage 1: per-(edge, col) message build + atomic scatter onto dst nodes.
__global__ __launch_bounds__(256) void edge_kernel(
    const float* __restrict__ nfeat,
    const int*   __restrict__ src,
    const int*   __restrict__ dst,
    const int*   __restrict__ eidx,
    const float* __restrict__ emb,
    float* __restrict__ neigh,
    float* __restrict__ deg,
    int E)
{
    long long tid = (long long)blockIdx.x * blockDim.x + threadIdx.x;
    long long total = (long long)E * D;
    if (tid >= total) return;
    int e = (int)(tid >> 7);
    int c = (int)(tid & (D - 1));

    int i0 = eidx[e * NF + 0];
    int i1 = eidx[e * NF + 1];
    int i2 = eidx[e * NF + 2];

    // edge_emb is [NF, V, D]; 12 KB total -> cache-resident
    float ef = emb[((0 * V) + i0) * D + c]
             + emb[((1 * V) + i1) * D + c]
             + emb[((2 * V) + i2) * D + c];

    float m = nfeat[(long long)src[e] * D + c] + ef;
    atomicAdd(&neigh[(long long)dst[e] * D + c], m);
    if (c == 0) atomicAdd(&deg[dst[e]], 1.0f);
}

// Stage 2: h = (nfeat + neigh) / (deg + 1); out = h @ W + b
// 16 rows per block, 128 threads (one per output column).
__global__ __launch_bounds__(128) void out_kernel(
    const float* __restrict__ nfeat,
    const float* __restrict__ neigh,
    const float* __restrict__ deg,
    const float* __restrict__ Wm,
    const float* __restrict__ bias,
    float* __restrict__ out,
    int N)
{
    __shared__ float sh[16][D];
    int row0 = blockIdx.x * 16;
    int col = threadIdx.x;

    for (int r = 0; r < 16; ++r) {
        int n = row0 + r;
        float h = 0.0f;
        if (n < N) {
            float dg = deg[n] + 1.0f;
            h = (nfeat[(long long)n * D + col] + neigh[(long long)n * D + col]) / dg;
        }
        sh[r][col] = h;
    }
    __syncthreads();

    float bv = bias[col];
    float acc[16];
#pragma unroll
    for (int r = 0; r < 16; ++r) acc[r] = bv;

    for (int k = 0; k < D; ++k) {
        float w = Wm[k * D + col];          // coalesced across lanes
#pragma unroll
        for (int r = 0; r < 16; ++r)
            acc[r] += sh[r][k] * w;         // sh[r][k] broadcast (same addr all lanes)
    }

#pragma unroll
    for (int r = 0; r < 16; ++r) {
        int n = row0 + r;
        if (n < N) out[(long long)n * D + col] = acc[r];
    }
}

extern "C" void kernel_launch(void* const* d_in, const int* in_sizes, int n_in,
                              void* d_out, int out_size, void* d_ws, size_t ws_size,
                              hipStream_t stream)
{
    const float* nfeat = (const float*)d_in[0];
    const int*   src   = (const int*)  d_in[1];
    const int*   dst   = (const int*)  d_in[2];
    const int*   eidx  = (const int*)  d_in[3];
    const float* emb   = (const float*)d_in[4];
    const float* Wm    = (const float*)d_in[5];
    const float* bias  = (const float*)d_in[6];
    float* out = (float*)d_out;

    int N = in_sizes[0] / D;   // 50000
    int E = in_sizes[1];       // 600000

    float* neigh = (float*)d_ws;
    float* deg   = neigh + (size_t)N * D;

    // ws is poisoned to 0xAA before every timed launch -> must zero here.
    hipMemsetAsync(d_ws, 0, ((size_t)N * D + N) * sizeof(float), stream);

    long long total = (long long)E * D;
    int blocks = (int)((total + 255) / 256);
    edge_kernel<<<blocks, 256, 0, stream>>>(nfeat, src, dst, eidx, emb, neigh, deg, E);

    out_kernel<<<(N + 15) / 16, 128, 0, stream>>>(nfeat, neigh, deg, Wm, bias, out, N);
}